// Round 12
// baseline (580.690 us; speedup 1.0000x reference)
//
#include <hip/hip_runtime.h>
#include <hip/hip_bf16.h>
#include <math.h>

#define N1 60000
#define N2 50000
#define DIM 128
#define NREL 16
#define NB 4
#define LCOM 100
#define LPAD 112  // LCOM padded to 7x16 for MFMA N-tiles

typedef __attribute__((ext_vector_type(8))) short short8;
typedef __attribute__((ext_vector_type(4))) float f32x4;
typedef __attribute__((ext_vector_type(4))) _Float16 half4;

__device__ __forceinline__ float bf2f(unsigned short u) {
    union { unsigned int i; float f; } c; c.i = ((unsigned int)u) << 16; return c.f;
}
__device__ __forceinline__ unsigned short f2bf(float f) {
    union { float f; unsigned int i; } c; c.f = f;
    unsigned int r = c.i + 0x7FFF + ((c.i >> 16) & 1);  // RNE
    return (unsigned short)(r >> 16);
}
__device__ __forceinline__ void split8(float4 a, float4 b, short8& h, short8& l) {
    float f[8] = {a.x, a.y, a.z, a.w, b.x, b.y, b.z, b.w};
#pragma unroll
    for (int j = 0; j < 8; j++) {
        unsigned short hh = f2bf(f[j]);
        h[j] = (short)hh;
        l[j] = (short)f2bf(f[j] - bf2f(hh));
    }
}

// ---------------- prelude: hist1 ∪ hist2 ∪ weight prep ∪ emb cast ----------------
__global__ __launch_bounds__(256) void k_prelude(
        const int* __restrict__ ei1, int E1, int* __restrict__ deg1, int HB1,
        const int* __restrict__ ei2, int E2, int* __restrict__ deg2, int HB2,
        const float* __restrict__ root1, const float* __restrict__ basis1,
        unsigned short* __restrict__ Wh1, unsigned short* __restrict__ Wl1,
        const float* __restrict__ root2, const float* __restrict__ basis2,
        unsigned short* __restrict__ Wh2, unsigned short* __restrict__ Wl2, int PB,
        const float* __restrict__ emb, _Float16* __restrict__ embh, int n4) {
    int b = blockIdx.x;
    if (b < HB1) {
        int e0 = b * 1024 + threadIdx.x;
#pragma unroll
        for (int j = 0; j < 4; j++) {
            int e = e0 + j * 256;
            if (e < E1) atomicAdd(deg1 + ei1[E1 + e], 1);
        }
    } else if (b < HB1 + HB2) {
        int e0 = (b - HB1) * 1024 + threadIdx.x;
#pragma unroll
        for (int j = 0; j < 4; j++) {
            int e = e0 + j * 256;
            if (e < E2) atomicAdd(deg2 + ei2[E2 + e], 1);
        }
    } else if (b < HB1 + HB2 + PB) {
        int t = (b - HB1 - HB2) * 256 + threadIdx.x;
        if (t < 2 * 640 * 128) {
            int which = t >= 640 * 128;
            int tt = which ? t - 640 * 128 : t;
            const float* root = which ? root2 : root1;
            const float* basis = which ? basis2 : basis1;
            unsigned short* Wh = which ? Wh2 : Wh1;
            unsigned short* Wl = which ? Wl2 : Wl1;
            int k = tt >> 7, n = tt & 127;
            float v = (k < 128) ? root[k * 128 + n] : basis[(k - 128) * 128 + n];
            unsigned short h = f2bf(v);
            Wh[n * 640 + k] = h;
            Wl[n * 640 + k] = f2bf(v - bf2f(h));
        }
    } else {
        int i = (b - HB1 - HB2 - PB) * 256 + threadIdx.x;
        if (i < n4) {
            float4 v = ((const float4*)emb)[i];
            half4 o = {(_Float16)v.x, (_Float16)v.y, (_Float16)v.z, (_Float16)v.w};
            ((half4*)embh)[i] = o;
        }
    }
}

// ---------------- merged hierarchical scan (two arrays per phase) ----------------
__global__ __launch_bounds__(256) void k_scan_p1m(const int* __restrict__ inA, int nA, int nbA,
                                                  int* __restrict__ bsumA,
                                                  const int* __restrict__ inB, int nB,
                                                  int* __restrict__ bsumB) {
    __shared__ int red[256];
    const int* in; int n; int* bsum; int b;
    if ((int)blockIdx.x < nbA) { in = inA; n = nA; bsum = bsumA; b = blockIdx.x; }
    else { in = inB; n = nB; bsum = bsumB; b = blockIdx.x - nbA; }
    int base = b * 1024;
    int tid = threadIdx.x;
    int s = 0;
#pragma unroll
    for (int j = 0; j < 4; j++) {
        int i = base + tid * 4 + j;
        if (i < n) s += in[i];
    }
    red[tid] = s;
    __syncthreads();
    for (int d = 128; d; d >>= 1) {
        if (tid < d) red[tid] += red[tid + d];
        __syncthreads();
    }
    if (tid == 0) bsum[b] = red[0];
}

__global__ __launch_bounds__(64) void k_scan_p2m(const int* __restrict__ bsumA, int* __restrict__ boffA,
                                                 int* __restrict__ offA, int nbA, int nA,
                                                 const int* __restrict__ bsumB, int* __restrict__ boffB,
                                                 int* __restrict__ offB, int nbB, int nB) {
    __shared__ int s[64];
    const int* bsum; int* boff; int* off; int nb; int n;
    if (blockIdx.x == 0) { bsum = bsumA; boff = boffA; off = offA; nb = nbA; n = nA; }
    else { bsum = bsumB; boff = boffB; off = offB; nb = nbB; n = nB; }
    int tid = threadIdx.x;
    int v = (tid < nb) ? bsum[tid] : 0;
    s[tid] = v;
    __syncthreads();
    for (int d = 1; d < 64; d <<= 1) {
        int t = (tid >= d) ? s[tid - d] : 0;
        __syncthreads();
        s[tid] += t;
        __syncthreads();
    }
    if (tid < nb) boff[tid] = s[tid] - v;
    if (tid == 63) off[n] = s[63];
}

__global__ __launch_bounds__(256) void k_scan_p3m(const int* __restrict__ inA, const int* __restrict__ boffA,
                                                  int* __restrict__ offA, int* __restrict__ curA,
                                                  int nA, int nbA,
                                                  const int* __restrict__ inB, const int* __restrict__ boffB,
                                                  int* __restrict__ offB, int* __restrict__ curB, int nB) {
    __shared__ int red[256];
    const int* in; const int* boff; int* off; int* cur; int n; int b;
    if ((int)blockIdx.x < nbA) { in = inA; boff = boffA; off = offA; cur = curA; n = nA; b = blockIdx.x; }
    else { in = inB; boff = boffB; off = offB; cur = curB; n = nB; b = blockIdx.x - nbA; }
    int base = b * 1024;
    int tid = threadIdx.x;
    int v[4];
    int s = 0;
#pragma unroll
    for (int j = 0; j < 4; j++) {
        int i = base + tid * 4 + j;
        v[j] = (i < n) ? in[i] : 0;
        s += v[j];
    }
    red[tid] = s;
    __syncthreads();
    for (int d = 1; d < 256; d <<= 1) {
        int t = (tid >= d) ? red[tid - d] : 0;
        __syncthreads();
        red[tid] += t;
        __syncthreads();
    }
    int run = boff[b] + red[tid] - s;
#pragma unroll
    for (int j = 0; j < 4; j++) {
        int i = base + tid * 4 + j;
        if (i < n) {
            off[i] = run; cur[i] = run;
            run += v[j];
        }
    }
}

// ---------------- both CSR scatters, block-ranged (4 edges/thread each) ----------------
__global__ void k_scat_both(const int* __restrict__ ei1, int E1, int* __restrict__ cur1,
                            int* __restrict__ elist1, int SB1,
                            const int* __restrict__ ei2, const int* __restrict__ et2, int E2,
                            int* __restrict__ cur2, int* __restrict__ elist2) {
    int b = blockIdx.x;
    if (b < SB1) {
        int e0 = b * 1024 + threadIdx.x;
#pragma unroll
        for (int j = 0; j < 4; j++) {
            int e = e0 + j * 256;
            if (e < E1) {
                int pos = atomicAdd(cur1 + ei1[E1 + e], 1);
                elist1[pos] = ei1[e];
            }
        }
    } else {
        int e0 = (b - SB1) * 1024 + threadIdx.x;
#pragma unroll
        for (int j = 0; j < 4; j++) {
            int e = e0 + j * 256;
            if (e < E2) {
                int pos = atomicAdd(cur2 + ei2[E2 + e], 1);
                elist2[pos] = (ei2[e] << 4) | et2[e];
            }
        }
    }
}

// ---------------- mix: concept_gather ∪ tyw ----------------
__global__ __launch_bounds__(256) void k_mix(
        const _Float16* __restrict__ embh, const float* __restrict__ emb,
        const int* __restrict__ off1, const int* __restrict__ elist1,
        float* __restrict__ xg1, _Float16* __restrict__ xg1h, int CONC_B,
        const int* __restrict__ lc, const float* __restrict__ w,
        unsigned short* __restrict__ tyh, unsigned short* __restrict__ tyl) {
    int b = blockIdx.x;
    if (b < CONC_B) {
        int node = b * 4 + (threadIdx.x >> 6);
        int lane = threadIdx.x & 63;
        if (node >= N2) return;
        int half = lane >> 5, d4 = (lane & 31) * 4;
        int s0 = off1[node], s1 = off1[node + 1];
        float4 acc = {0.f, 0.f, 0.f, 0.f};
        int i = s0;
        for (; i + 4 <= s1; i += 4) {
            int sa = elist1[i + half];
            int sb = elist1[i + 2 + half];
            half4 ha = *(const half4*)(embh + (size_t)sa * DIM + d4);
            half4 hb = *(const half4*)(embh + (size_t)sb * DIM + d4);
            acc.x += (float)ha[0] + (float)hb[0];
            acc.y += (float)ha[1] + (float)hb[1];
            acc.z += (float)ha[2] + (float)hb[2];
            acc.w += (float)ha[3] + (float)hb[3];
        }
        for (; i < s1; i += 2) {
            int e = i + half;
            bool ok = e < s1;
            int s = elist1[ok ? e : i];
            half4 hv = *(const half4*)(embh + (size_t)s * DIM + d4);
            if (ok) {
                acc.x += (float)hv[0]; acc.y += (float)hv[1];
                acc.z += (float)hv[2]; acc.w += (float)hv[3];
            }
        }
        acc.x += __shfl_xor(acc.x, 32, 64);
        acc.y += __shfl_xor(acc.y, 32, 64);
        acc.z += __shfl_xor(acc.z, 32, 64);
        acc.w += __shfl_xor(acc.w, 32, 64);
        if (half == 0) {
            float inv = 1.0f / (float)max(s1 - s0, 1);
            float4 e = *(const float4*)(emb + (size_t)node * DIM + d4);
            float4 o = {fmaxf(e.x + acc.x * inv, 0.f), fmaxf(e.y + acc.y * inv, 0.f),
                        fmaxf(e.z + acc.z * inv, 0.f), fmaxf(e.w + acc.w * inv, 0.f)};
            *(float4*)(xg1 + (size_t)node * DIM + d4) = o;
            half4 oh = {(_Float16)o.x, (_Float16)o.y, (_Float16)o.z, (_Float16)o.w};
            *(half4*)(xg1h + (size_t)node * DIM + d4) = oh;
        }
    } else {
        if (threadIdx.x >= 64) return;
        int l = b - CONC_B;
        int lane = threadIdx.x;
        int d0 = lane * 2;
        if (l >= LCOM) {
            ushort2 z = {0, 0};
            *(ushort2*)(tyh + (size_t)l * 128 + d0) = z;
            *(ushort2*)(tyl + (size_t)l * 128 + d0) = z;
            return;
        }
        int row = lc[l];
        int s0 = off1[row], s1 = off1[row + 1];
        float2 acc = {0.f, 0.f};
        for (int i = s0; i < s1; i++) {
            int s = elist1[i];
            float2 v = *(const float2*)(emb + (size_t)s * DIM + lane * 2);
            acc.x += v.x; acc.y += v.y;
        }
        float inv = 1.0f / (float)max(s1 - s0, 1);
        float2 e = *(const float2*)(emb + (size_t)row * DIM + lane * 2);
        float v0 = fmaxf(e.x + acc.x * inv, 0.f) * w[d0];
        float v1 = fmaxf(e.y + acc.y * inv, 0.f) * w[d0 + 1];
        unsigned short h0 = f2bf(v0), h1 = f2bf(v1);
        ushort2 hh = {h0, h1};
        ushort2 ll = {f2bf(v0 - bf2f(h0)), f2bf(v1 - bf2f(h1))};
        *(ushort2*)(tyh + (size_t)l * 128 + d0) = hh;
        *(ushort2*)(tyl + (size_t)l * 128 + d0) = ll;
    }
}

// ---------------- rgcn aggregation: fp16 gather, inline per-node type counts ----------------
__global__ __launch_bounds__(256) void k_rgcn_gather(const _Float16* __restrict__ xh,
                                                     const int* __restrict__ off,
                                                     const int* __restrict__ elist,
                                                     const float* __restrict__ comp,
                                                     float* __restrict__ agg, int n) {
    __shared__ float scomp[NREL * NB];
    __shared__ float nrmlds[4][NREL];
    if (threadIdx.x < NREL * NB) scomp[threadIdx.x] = comp[threadIdx.x];
    __syncthreads();
    int nb = threadIdx.x >> 6;
    int node = blockIdx.x * 4 + nb;
    int lane = threadIdx.x & 63;
    if (node >= n) return;
    int s0 = off[node], s1 = off[node + 1];
    unsigned long long c0 = 0, c1 = 0;
    for (int i = s0 + lane; i < s1; i += 64) {
        int t = elist[i] & 15;
        if (t < 8) c0 += 1ull << (8 * t); else c1 += 1ull << (8 * (t - 8));
    }
#pragma unroll
    for (int o = 32; o; o >>= 1) {
        c0 += __shfl_xor(c0, o, 64);
        c1 += __shfl_xor(c1, o, 64);
    }
    if (lane < NREL) {
        unsigned int c = (lane < 8) ? (unsigned int)((c0 >> (8 * lane)) & 255)
                                    : (unsigned int)((c1 >> (8 * (lane - 8))) & 255);
        nrmlds[nb][lane] = 1.0f / (float)max(c, 1u);
    }
    int half = lane >> 5, d4 = (lane & 31) * 4;
    float4 a0 = {0, 0, 0, 0}, a1 = a0, a2 = a0, a3 = a0;
    int i = s0;
#define RG_EDGE(E_IDX, GATE)                                                   \
    {                                                                          \
        int p = elist[E_IDX];                                                  \
        int s = p >> 4, t = p & 15;                                            \
        float nr = nrmlds[nb][t] * (GATE);                                     \
        float4 cf = *(const float4*)(scomp + t * 4);                           \
        half4 hv = *(const half4*)(xh + (size_t)s * DIM + d4);                 \
        float4 v = {(float)hv[0], (float)hv[1], (float)hv[2], (float)hv[3]};   \
        float c0_ = cf.x * nr, c1_ = cf.y * nr, c2_ = cf.z * nr, c3_ = cf.w * nr; \
        a0.x = fmaf(c0_, v.x, a0.x); a0.y = fmaf(c0_, v.y, a0.y);              \
        a0.z = fmaf(c0_, v.z, a0.z); a0.w = fmaf(c0_, v.w, a0.w);              \
        a1.x = fmaf(c1_, v.x, a1.x); a1.y = fmaf(c1_, v.y, a1.y);              \
        a1.z = fmaf(c1_, v.z, a1.z); a1.w = fmaf(c1_, v.w, a1.w);              \
        a2.x = fmaf(c2_, v.x, a2.x); a2.y = fmaf(c2_, v.y, a2.y);              \
        a2.z = fmaf(c2_, v.z, a2.z); a2.w = fmaf(c2_, v.w, a2.w);              \
        a3.x = fmaf(c3_, v.x, a3.x); a3.y = fmaf(c3_, v.y, a3.y);              \
        a3.z = fmaf(c3_, v.z, a3.z); a3.w = fmaf(c3_, v.w, a3.w);              \
    }
    for (; i + 4 <= s1; i += 4) {
        RG_EDGE(i + half, 1.0f);
        RG_EDGE(i + 2 + half, 1.0f);
    }
    for (; i < s1; i += 2) {
        int e = i + half;
        bool ok = e < s1;
        int ei_ = ok ? e : i;
        RG_EDGE(ei_, ok ? 1.0f : 0.0f);
    }
#undef RG_EDGE
    a0.x += __shfl_xor(a0.x, 32, 64); a0.y += __shfl_xor(a0.y, 32, 64);
    a0.z += __shfl_xor(a0.z, 32, 64); a0.w += __shfl_xor(a0.w, 32, 64);
    a1.x += __shfl_xor(a1.x, 32, 64); a1.y += __shfl_xor(a1.y, 32, 64);
    a1.z += __shfl_xor(a1.z, 32, 64); a1.w += __shfl_xor(a1.w, 32, 64);
    a2.x += __shfl_xor(a2.x, 32, 64); a2.y += __shfl_xor(a2.y, 32, 64);
    a2.z += __shfl_xor(a2.z, 32, 64); a2.w += __shfl_xor(a2.w, 32, 64);
    a3.x += __shfl_xor(a3.x, 32, 64); a3.y += __shfl_xor(a3.y, 32, 64);
    a3.z += __shfl_xor(a3.z, 32, 64); a3.w += __shfl_xor(a3.w, 32, 64);
    if (half == 0) {
        float* o = agg + (size_t)node * (NB * DIM) + d4;
        *(float4*)(o + 0 * DIM) = a0;
        *(float4*)(o + 1 * DIM) = a1;
        *(float4*)(o + 2 * DIM) = a2;
        *(float4*)(o + 3 * DIM) = a3;
    }
}

// ---------------- split-precision MFMA GEMM, BM=64 (782 blocks: fixes tail quantization) ----------------
#define LDSK 40
__global__ __launch_bounds__(256) void k_gemm(const float* __restrict__ x,
                                              const float* __restrict__ agg,
                                              const unsigned short* __restrict__ Wh,
                                              const unsigned short* __restrict__ Wl,
                                              const float* __restrict__ bias,
                                              float* __restrict__ out,
                                              _Float16* __restrict__ out_h, int relu) {
    __shared__ __align__(16) short Ah[64 * LDSK];
    __shared__ __align__(16) short Al[64 * LDSK];
    __shared__ __align__(16) short Bh[128 * LDSK];
    __shared__ __align__(16) short Bl[128 * LDSK];
    int tid = threadIdx.x;
    int lane = tid & 63, wid = tid >> 6;
    int wave_m = wid & 1, wave_n = wid >> 1;   // wave tile 32x64
    int l15 = lane & 15, quad = lane >> 4;
    int row0 = blockIdx.x * 64;

    int arow_s = tid >> 2, akh = (tid & 3) * 8;   // A-staging: 64 rows x 32 k, 8/thread
    int brow_s = tid >> 1, bkh = (tid & 1) * 16;  // B-staging: 128 rows x 32 k, 16/thread

    f32x4 acc[2][4] = {};
    for (int k0 = 0; k0 < 640; k0 += 32) {
        {
            int rg = row0 + arow_s;
            float4 q0 = {0, 0, 0, 0}, q1 = q0;
            if (rg < N2) {
                const float* src = (k0 < 128) ? (x + (size_t)rg * 128 + k0 + akh)
                                              : (agg + (size_t)rg * 512 + (k0 - 128) + akh);
                q0 = *(const float4*)(src + 0);
                q1 = *(const float4*)(src + 4);
            }
            short8 h0, l0;
            split8(q0, q1, h0, l0);
            *(short8*)(&Ah[arow_s * LDSK + akh]) = h0;
            *(short8*)(&Al[arow_s * LDSK + akh]) = l0;
        }
        {
            const unsigned short* sh = Wh + (size_t)brow_s * 640 + k0 + bkh;
            const unsigned short* sl = Wl + (size_t)brow_s * 640 + k0 + bkh;
            *(short8*)(&Bh[brow_s * LDSK + bkh]) = *(const short8*)(sh);
            *(short8*)(&Bh[brow_s * LDSK + bkh + 8]) = *(const short8*)(sh + 8);
            *(short8*)(&Bl[brow_s * LDSK + bkh]) = *(const short8*)(sl);
            *(short8*)(&Bl[brow_s * LDSK + bkh + 8]) = *(const short8*)(sl + 8);
        }
        __syncthreads();
        short8 ah[2], al[2], bh[4], bl[4];
#pragma unroll
        for (int i = 0; i < 2; i++) {
            int ro = (wave_m * 32 + i * 16 + l15) * LDSK + quad * 8;
            ah[i] = *(const short8*)(&Ah[ro]);
            al[i] = *(const short8*)(&Al[ro]);
        }
#pragma unroll
        for (int j = 0; j < 4; j++) {
            int ro = (wave_n * 64 + j * 16 + l15) * LDSK + quad * 8;
            bh[j] = *(const short8*)(&Bh[ro]);
            bl[j] = *(const short8*)(&Bl[ro]);
        }
#pragma unroll
        for (int i = 0; i < 2; i++)
#pragma unroll
            for (int j = 0; j < 4; j++) {
                acc[i][j] = __builtin_amdgcn_mfma_f32_16x16x32_bf16(al[i], bh[j], acc[i][j], 0, 0, 0);
                acc[i][j] = __builtin_amdgcn_mfma_f32_16x16x32_bf16(ah[i], bl[j], acc[i][j], 0, 0, 0);
                acc[i][j] = __builtin_amdgcn_mfma_f32_16x16x32_bf16(ah[i], bh[j], acc[i][j], 0, 0, 0);
            }
        __syncthreads();
    }
#pragma unroll
    for (int j = 0; j < 4; j++) {
        int gcol = wave_n * 64 + j * 16 + l15;
        float bv = bias[gcol];
#pragma unroll
        for (int i = 0; i < 2; i++) {
            int grow_base = row0 + wave_m * 32 + i * 16 + quad * 4;
#pragma unroll
            for (int r = 0; r < 4; r++) {
                int grow = grow_base + r;
                if (grow >= N2) continue;
                float v = acc[i][j][r] + bv;
                if (relu) v = fmaxf(v, 0.f);
                out[(size_t)grow * 128 + gcol] = v;
                if (out_h) out_h[(size_t)grow * 128 + gcol] = (_Float16)v;
            }
        }
    }
}

// ---------------- logits + softmax: MFMA, no LDS ----------------
__global__ __launch_bounds__(256) void k_logits(const float* __restrict__ h2,
                                                const unsigned short* __restrict__ tyh,
                                                const unsigned short* __restrict__ tyl,
                                                float* __restrict__ out, int M) {
    int wid = threadIdx.x >> 6, lane = threadIdx.x & 63;
    int l15 = lane & 15, quad = lane >> 4;
    int row0w = blockIdx.x * 64 + wid * 16;
    int arow = min(row0w + l15, M - 1);
    f32x4 acc[7] = {};
#pragma unroll
    for (int k0 = 0; k0 < 128; k0 += 32) {
        const float* ap = h2 + (size_t)arow * 128 + k0 + quad * 8;
        float4 q0 = *(const float4*)(ap);
        float4 q1 = *(const float4*)(ap + 4);
        short8 ah, al;
        split8(q0, q1, ah, al);
#pragma unroll
        for (int j = 0; j < 7; j++) {
            size_t bo = (size_t)(j * 16 + l15) * 128 + k0 + quad * 8;
            short8 bh = *(const short8*)(tyh + bo);
            short8 bl = *(const short8*)(tyl + bo);
            acc[j] = __builtin_amdgcn_mfma_f32_16x16x32_bf16(al, bh, acc[j], 0, 0, 0);
            acc[j] = __builtin_amdgcn_mfma_f32_16x16x32_bf16(ah, bl, acc[j], 0, 0, 0);
            acc[j] = __builtin_amdgcn_mfma_f32_16x16x32_bf16(ah, bh, acc[j], 0, 0, 0);
        }
    }
    bool v6 = (l15 < LCOM - 96);
#pragma unroll
    for (int r = 0; r < 4; r++) {
        int grow = row0w + quad * 4 + r;
        float m = -INFINITY;
#pragma unroll
        for (int j = 0; j < 6; j++) m = fmaxf(m, acc[j][r]);
        if (v6) m = fmaxf(m, acc[6][r]);
        m = fmaxf(m, __shfl_xor(m, 8, 64));
        m = fmaxf(m, __shfl_xor(m, 4, 64));
        m = fmaxf(m, __shfl_xor(m, 2, 64));
        m = fmaxf(m, __shfl_xor(m, 1, 64));
        float e[7];
        float s = 0.f;
#pragma unroll
        for (int j = 0; j < 6; j++) { e[j] = __expf(acc[j][r] - m); s += e[j]; }
        e[6] = v6 ? __expf(acc[6][r] - m) : 0.f;
        s += e[6];
        s += __shfl_xor(s, 8, 64);
        s += __shfl_xor(s, 4, 64);
        s += __shfl_xor(s, 2, 64);
        s += __shfl_xor(s, 1, 64);
        float inv = 1.0f / s;
        if (grow < M) {
#pragma unroll
            for (int j = 0; j < 6; j++) out[(size_t)grow * LCOM + j * 16 + l15] = e[j] * inv;
            if (v6) out[(size_t)grow * LCOM + 96 + l15] = e[6] * inv;
        }
    }
}

extern "C" void kernel_launch(void* const* d_in, const int* in_sizes, int n_in,
                              void* d_out, int out_size, void* d_ws, size_t ws_size,
                              hipStream_t stream) {
    const int* ei2 = (const int*)d_in[0];
    const int* et2 = (const int*)d_in[1];
    const int* ei1 = (const int*)d_in[2];
    const int* lc = (const int*)d_in[3];
    const float* emb = (const float*)d_in[4];
    const float* basis1 = (const float*)d_in[5];
    const float* comp1 = (const float*)d_in[6];
    const float* root1 = (const float*)d_in[7];
    const float* bias1 = (const float*)d_in[8];
    const float* basis2 = (const float*)d_in[9];
    const float* comp2 = (const float*)d_in[10];
    const float* root2 = (const float*)d_in[11];
    const float* bias2 = (const float*)d_in[12];
    const float* wts = (const float*)d_in[13];
    float* out = (float*)d_out;
    int E2 = in_sizes[0] / 2, E1 = in_sizes[2] / 2;

    float* ws = (float*)d_ws;
    float* xg1 = ws;                          // 6,400,000 f (reused as h2)
    float* h1 = xg1 + 6400000;                // 6,400,000 f (first half aliased as xg1_h)
    float* agg = h1 + 6400000;                // 25,600,000 f
    _Float16* emb_h = (_Float16*)(agg + 25600000);  // 7,680,000 h (first 6.4M aliased as h1_h)
    unsigned short* tyh = (unsigned short*)(emb_h + 7680000);  // 14,336
    unsigned short* tyl = tyh + LPAD * 128;                    // 14,336
    unsigned short* Wh1 = tyl + LPAD * 128;   // 81,920 each
    unsigned short* Wl1 = Wh1 + 81920;
    unsigned short* Wh2 = Wl1 + 81920;
    unsigned short* Wl2 = Wh2 + 81920;
    int* ipool = (int*)(Wl2 + 81920);
    int* deg1 = ipool;                        // 60,000 (deg1+deg2 adjacent: one memset)
    int* deg2 = deg1 + 60000;                 // 50,000
    int* off1 = deg2 + 50000;                 // 60,001
    int* cur1 = off1 + 60001;                 // 60,000
    int* elist1 = cur1 + 60000;               // 800,000
    int* off2 = elist1 + 800000;              // 50,001
    int* cur2 = off2 + 50001;                 // 50,000
    int* elist2 = cur2 + 50000;               // 800,000
    int* bsum1 = elist2 + 800000;             // 64
    int* boff1 = bsum1 + 64;
    int* bsum2 = boff1 + 64;
    int* boff2 = bsum2 + 64;
    _Float16* xg1_h = (_Float16*)h1;          // alias: gather1 consumes xg1_h before gemm1 writes h1
    _Float16* h1_h = emb_h;                   // alias: emb_h consumed by k_mix before gemm1 writes
    float* h2 = xg1;                          // alias: xg1 dead after gemm1

    const int NB1 = (N1 + 1023) / 1024;       // 59
    const int NB2 = (N2 + 1023) / 1024;       // 49
    const int HB1 = (E1 + 1023) / 1024;
    const int HB2 = (E2 + 1023) / 1024;
    const int PB = (2 * 640 * 128) / 256;     // 640
    const int CB = (N1 * DIM / 4 + 255) / 256;  // 7500
    const int CONC_B = (N2 + 3) / 4;          // 12500

    // 1) zero degree arrays
    hipMemsetAsync(deg1, 0, (60000 + 50000) * sizeof(int), stream);

    // 2) prelude: hist1 ∪ hist2 ∪ weight prep ∪ emb cast
    k_prelude<<<HB1 + HB2 + PB + CB, 256, 0, stream>>>(
        ei1, E1, deg1, HB1, ei2, E2, deg2, HB2,
        root1, basis1, Wh1, Wl1, root2, basis2, Wh2, Wl2, PB,
        emb, emb_h, N1 * DIM / 4);

    // 3-5) merged scans for both CSRs
    k_scan_p1m<<<NB1 + NB2, 256, 0, stream>>>(deg1, N1, NB1, bsum1, deg2, N2, bsum2);
    k_scan_p2m<<<2, 64, 0, stream>>>(bsum1, boff1, off1, NB1, N1, bsum2, boff2, off2, NB2, N2);
    k_scan_p3m<<<NB1 + NB2, 256, 0, stream>>>(deg1, boff1, off1, cur1, N1, NB1,
                                              deg2, boff2, off2, cur2, N2);

    // 6) both scatters, block-ranged
    k_scat_both<<<HB1 + HB2, 256, 0, stream>>>(ei1, E1, cur1, elist1, HB1,
                                               ei2, et2, E2, cur2, elist2);

    // 7) mix: concept ∪ tyw
    k_mix<<<CONC_B + LPAD, 256, 0, stream>>>(
        emb_h, emb, off1, elist1, xg1, xg1_h, CONC_B, lc, wts, tyh, tyl);

    // 8-9) rgcn layer 1
    k_rgcn_gather<<<CONC_B, 256, 0, stream>>>(xg1_h, off2, elist2, comp1, agg, N2);
    k_gemm<<<(N2 + 63) / 64, 256, 0, stream>>>(xg1, agg, Wh1, Wl1, bias1, h1, h1_h, 1);

    // 10-11) rgcn layer 2
    k_rgcn_gather<<<CONC_B, 256, 0, stream>>>(h1_h, off2, elist2, comp2, agg, N2);
    k_gemm<<<(N2 + 63) / 64, 256, 0, stream>>>(h1, agg, Wh2, Wl2, bias2, h2, (_Float16*)nullptr, 0);

    // 12) logits + softmax
    k_logits<<<(N2 + 63) / 64, 256, 0, stream>>>(h2, tyh, tyl, out, N2);
}